// Round 1
// baseline (338.149 us; speedup 1.0000x reference)
//
#include <hip/hip_runtime.h>

#define NROWS 524288
#define BM 32
#define THREADS 512
#define BLOCKS 512
#define TILES_PER_BLOCK (NROWS / BM / BLOCKS)   // 32

using bf16x8 = __bf16 __attribute__((ext_vector_type(8)));
using f32x4  = float  __attribute__((ext_vector_type(4)));

__device__ __forceinline__ f32x4 mfma16(bf16x8 a, bf16x8 b, f32x4 c) {
    return __builtin_amdgcn_mfma_f32_16x16x32_bf16(a, b, c, 0, 0, 0);
}

// h = silu(z), sp = silu'(z) = s*(1 + z*(1-s)) = s + h*(1-s)
__device__ __forceinline__ void silu2(float z, float& h, float& sp) {
    float s = __builtin_amdgcn_rcpf(1.0f + __expf(-z));
    h = z * s;
    sp = fmaf(h, 1.0f - s, s);
}

__global__ __launch_bounds__(THREADS) void cnf_kernel(
    const float* __restrict__ y, const float* __restrict__ tp,
    const float* __restrict__ v,
    const float* __restrict__ W1, const float* __restrict__ b1,
    const float* __restrict__ W2, const float* __restrict__ b2,
    const float* __restrict__ W3, const float* __restrict__ b3,
    const float* __restrict__ W4, const float* __restrict__ b4,
    float* __restrict__ out)
{
    // weights, both orientations where MFMA needs them (K-contiguous rows)
    __shared__ __align__(16) __bf16 sBW2T[128][136]; // [b][a] = W2[a][b]  (fwd G2 B)
    __shared__ __align__(16) __bf16 sAW2 [128][136]; // [a][b] = W2        (bwd b1 B)
    __shared__ __align__(16) __bf16 sBW3T[ 64][136]; // [c][b] = W3[b][c]  (fwd G3 B)
    __shared__ __align__(16) __bf16 sAW3 [128][ 72]; // [b][c] = W3        (bwd b2 B)
    // activations (per 32-row tile)
    __shared__ __align__(16) __bf16 sH1 [BM][136];   // h1, later d2
    __shared__ __align__(16) __bf16 sSP1[BM][136];
    __shared__ __align__(16) __bf16 sH2 [BM][136];
    __shared__ __align__(16) __bf16 sSP2[BM][136];
    __shared__ __align__(16) __bf16 sD3 [BM][ 72];
    __shared__ float sW1[3][128];
    __shared__ float sb1[128], sb2[128], sb3[64];
    __shared__ float sW4[64][2], sb4v[2];
    __shared__ float sy[BM][2], sv[BM][2];
    __shared__ float dyAcc[BM][2], divAcc[BM];

    const int tid = threadIdx.x;

    // ---- stage weights once per block ----
    for (int i = tid; i < 128*128; i += THREADS) {
        int a = i >> 7, b = i & 127;
        __bf16 w = (__bf16)W2[i];
        sAW2[a][b] = w; sBW2T[b][a] = w;
    }
    for (int i = tid; i < 128*64; i += THREADS) {
        int bb = i >> 6, c = i & 63;
        __bf16 w = (__bf16)W3[i];
        sAW3[bb][c] = w; sBW3T[c][bb] = w;
    }
    if (tid < 384) ((float*)sW1)[tid] = W1[tid];
    if (tid < 128) sb1[tid] = b1[tid];
    if (tid < 128) sb2[tid] = b2[tid];
    if (tid <  64) sb3[tid] = b3[tid];
    if (tid < 128) ((float*)sW4)[tid] = W4[tid];
    if (tid <   2) sb4v[tid] = b4[tid];
    __syncthreads();

    const float tval = tp[0];
    // layer-1 per-thread constants (col a1, 8 rows each)
    const int a1 = tid & 127, rg = tid >> 7;
    const float w1a = sW1[0][a1], w1b = sW1[1][a1];
    const float c1  = fmaf(tval, sW1[2][a1], sb1[a1]);

    const int w = tid >> 6, lane = tid & 63, g = lane >> 4, q = lane & 15;
    const int mt = w >> 2, ntp = w & 3;     // 2 M-tiles x 4 N-groups
    const int rrb = 16*mt + 4*g;

    const int tile0 = blockIdx.x * TILES_PER_BLOCK;
    for (int tile = tile0; tile < tile0 + TILES_PER_BLOCK; ++tile) {
        const int row0 = tile * BM;

        if (tid < 64) {
            sy[tid>>1][tid&1] = y[row0*2 + tid];
            sv[tid>>1][tid&1] = v[row0*2 + tid];
            dyAcc[tid>>1][tid&1] = sb4v[tid&1];
        }
        if (tid < 32) divAcc[tid] = 0.0f;   // same threads that read it below
        __syncthreads();                    // Bs

        // ---- P1: layer 1 (VALU f32) ----
        #pragma unroll
        for (int j = 0; j < 8; ++j) {
            int r = rg*8 + j;
            float z = fmaf(sy[r][0], w1a, fmaf(sy[r][1], w1b, c1));
            float h, sp; silu2(z, h, sp);
            sH1[r][a1] = (__bf16)h; sSP1[r][a1] = (__bf16)sp;
        }
        __syncthreads();                    // B1

        // ---- P2: z2 = h1 @ W2 (+b2), silu ----
        {
            f32x4 acc0 = {0,0,0,0}, acc1 = {0,0,0,0};
            const __bf16* ar  = &sH1[16*mt + q][0];
            const __bf16* br0 = &sBW2T[16*(2*ntp)   + q][0];
            const __bf16* br1 = &sBW2T[16*(2*ntp+1) + q][0];
            #pragma unroll
            for (int ks = 0; ks < 4; ++ks) {
                int ko = 8*g + 32*ks;
                bf16x8 av = *(const bf16x8*)(ar + ko);
                acc0 = mfma16(av, *(const bf16x8*)(br0 + ko), acc0);
                acc1 = mfma16(av, *(const bf16x8*)(br1 + ko), acc1);
            }
            #pragma unroll
            for (int nti = 0; nti < 2; ++nti) {
                int cc = q + 16*(2*ntp + nti);
                float bias = sb2[cc];
                f32x4 acc = nti ? acc1 : acc0;
                #pragma unroll
                for (int reg = 0; reg < 4; ++reg) {
                    int rr = rrb + reg;
                    float z = acc[reg] + bias;
                    float h, sp; silu2(z, h, sp);
                    sH2[rr][cc] = (__bf16)h; sSP2[rr][cc] = (__bf16)sp;
                }
            }
        }
        __syncthreads();                    // B2

        // ---- P3: z3 = h2 @ W3 (+b3); epi: d3 = (v.W4).silu', dy partials ----
        {
            f32x4 acc = {0,0,0,0};
            const __bf16* ar = &sH2[16*mt + q][0];
            const __bf16* br = &sBW3T[16*ntp + q][0];
            #pragma unroll
            for (int ks = 0; ks < 4; ++ks) {
                int ko = 8*g + 32*ks;
                acc = mfma16(*(const bf16x8*)(ar + ko), *(const bf16x8*)(br + ko), acc);
            }
            int cc = q + 16*ntp;
            float w40 = sW4[cc][0], w41 = sW4[cc][1], bias = sb3[cc];
            #pragma unroll
            for (int reg = 0; reg < 4; ++reg) {
                int rr = rrb + reg;
                float z = acc[reg] + bias;
                float h, sp; silu2(z, h, sp);
                float g3 = fmaf(sv[rr][0], w40, sv[rr][1]*w41);
                sD3[rr][cc] = (__bf16)(g3*sp);
                float p0 = h*w40, p1 = h*w41;
                #pragma unroll
                for (int m = 1; m <= 8; m <<= 1) {
                    p0 += __shfl_xor(p0, m);
                    p1 += __shfl_xor(p1, m);
                }
                if (q == 0) {
                    atomicAdd(&dyAcc[rr][0], p0);
                    atomicAdd(&dyAcc[rr][1], p1);
                }
            }
        }
        __syncthreads();                    // B3

        // dy writeout + P4: g2 = d3 @ W3^T ; d2 = g2 * sp2 -> sH1
        if (tid < 64) out[row0*2 + tid] = dyAcc[tid>>1][tid&1];
        {
            f32x4 acc0 = {0,0,0,0}, acc1 = {0,0,0,0};
            const __bf16* ar  = &sD3[16*mt + q][0];
            const __bf16* br0 = &sAW3[16*(2*ntp)   + q][0];
            const __bf16* br1 = &sAW3[16*(2*ntp+1) + q][0];
            #pragma unroll
            for (int ks = 0; ks < 2; ++ks) {
                int ko = 8*g + 32*ks;
                bf16x8 av = *(const bf16x8*)(ar + ko);
                acc0 = mfma16(av, *(const bf16x8*)(br0 + ko), acc0);
                acc1 = mfma16(av, *(const bf16x8*)(br1 + ko), acc1);
            }
            #pragma unroll
            for (int nti = 0; nti < 2; ++nti) {
                int cc = q + 16*(2*ntp + nti);
                f32x4 acc = nti ? acc1 : acc0;
                #pragma unroll
                for (int reg = 0; reg < 4; ++reg) {
                    int rr = rrb + reg;
                    float d2 = acc[reg] * (float)sSP2[rr][cc];
                    sH1[rr][cc] = (__bf16)d2;
                }
            }
        }
        __syncthreads();                    // B4

        // ---- P5: g1 = d2 @ W2^T ; d1 = g1*sp1 ; div partials ----
        {
            f32x4 acc0 = {0,0,0,0}, acc1 = {0,0,0,0};
            const __bf16* ar  = &sH1[16*mt + q][0];   // d2
            const __bf16* br0 = &sAW2[16*(2*ntp)   + q][0];
            const __bf16* br1 = &sAW2[16*(2*ntp+1) + q][0];
            #pragma unroll
            for (int ks = 0; ks < 4; ++ks) {
                int ko = 8*g + 32*ks;
                bf16x8 av = *(const bf16x8*)(ar + ko);
                acc0 = mfma16(av, *(const bf16x8*)(br0 + ko), acc0);
                acc1 = mfma16(av, *(const bf16x8*)(br1 + ko), acc1);
            }
            #pragma unroll
            for (int nti = 0; nti < 2; ++nti) {
                int aa = q + 16*(2*ntp + nti);
                float wa0 = sW1[0][aa], wa1 = sW1[1][aa];
                f32x4 acc = nti ? acc1 : acc0;
                #pragma unroll
                for (int reg = 0; reg < 4; ++reg) {
                    int rr = rrb + reg;
                    float d1 = acc[reg] * (float)sSP1[rr][aa];
                    float s = d1 * fmaf(wa0, sv[rr][0], wa1*sv[rr][1]);
                    #pragma unroll
                    for (int m = 1; m <= 8; m <<= 1) s += __shfl_xor(s, m);
                    if (q == 0) atomicAdd(&divAcc[rr], s);
                }
            }
        }
        __syncthreads();                    // B5

        if (tid < 32) out[2*NROWS + row0 + tid] = -divAcc[tid];
        // next-iter staging is safe without another barrier:
        // divAcc re-init by the same tid<32 threads; sy/sv/dyAcc writers are
        // barrier-separated from their last readers.
    }
}

extern "C" void kernel_launch(void* const* d_in, const int* in_sizes, int n_in,
                              void* d_out, int out_size, void* d_ws, size_t ws_size,
                              hipStream_t stream) {
    const float* y  = (const float*)d_in[0];
    // d_in[1] = logp (unused by reference)
    const float* t  = (const float*)d_in[2];
    const float* v  = (const float*)d_in[3];
    const float* W1 = (const float*)d_in[4];
    const float* b1 = (const float*)d_in[5];
    const float* W2 = (const float*)d_in[6];
    const float* b2 = (const float*)d_in[7];
    const float* W3 = (const float*)d_in[8];
    const float* b3 = (const float*)d_in[9];
    const float* W4 = (const float*)d_in[10];
    const float* b4 = (const float*)d_in[11];
    float* out = (float*)d_out;

    cnf_kernel<<<dim3(BLOCKS), dim3(THREADS), 0, stream>>>(
        y, t, v, W1, b1, W2, b2, W3, b3, W4, b4, out);
}

// Round 2
// 153.630 us; speedup vs baseline: 2.2011x; 2.2011x over previous
//
#include <hip/hip_runtime.h>

#define NROWS 524288
#define BM 32
#define THREADS 512
#define BLOCKS 1024
#define TILES_PER_BLOCK (NROWS / BM / BLOCKS)   // 16

using bf16x8 = __bf16 __attribute__((ext_vector_type(8)));
using f32x4  = float  __attribute__((ext_vector_type(4)));

__device__ __forceinline__ f32x4 mfma16(bf16x8 a, bf16x8 b, f32x4 c) {
    return __builtin_amdgcn_mfma_f32_16x16x32_bf16(a, b, c, 0, 0, 0);
}

// h = silu(z), sp = silu'(z) = s + h*(1-s)
__device__ __forceinline__ void silu2(float z, float& h, float& sp) {
    float s = __builtin_amdgcn_rcpf(1.0f + __expf(-z));
    h = z * s;
    sp = fmaf(h, 1.0f - s, s);
}

__global__ __launch_bounds__(THREADS, 4) void cnf_kernel(
    const float* __restrict__ y, const float* __restrict__ tp,
    const float* __restrict__ v,
    const float* __restrict__ W1, const float* __restrict__ b1,
    const float* __restrict__ W2, const float* __restrict__ b2,
    const float* __restrict__ W3, const float* __restrict__ b3,
    const float* __restrict__ W4, const float* __restrict__ b4,
    float* __restrict__ out)
{
    // LDS: 80,640 B total -> 2 blocks/CU
    __shared__ __align__(16) __bf16 sBW2T[128][136]; // W2^T  (fwd P2 B)   34816
    __shared__ __align__(16) __bf16 sAW3 [128][72];  // W3    (bwd P4 B)   18432
    __shared__ __align__(16) __bf16 sH1 [BM][136];   // h1, then d2         8704
    __shared__ __align__(16) __bf16 sH2 [BM][136];   // h2, then d1         8704
    __shared__ __align__(16) __bf16 sD3 [BM][72];    //                     4608
    __shared__ __align__(16) __bf16 sH3 [BM][72];    //                     4608
    __shared__ float sy[BM][2];                      //                      256
    __shared__ float sv[2][BM][2];                   //                      512

    const int tid  = threadIdx.x;
    const int w    = tid >> 6, lane = tid & 63, g = lane >> 4, q = lane & 15;
    const int mt   = w >> 2, ntp = w & 3;            // 2 M-tiles x 4 N-groups
    const int colA = 32*ntp + q, colB = 32*ntp + 16 + q, c3 = 16*ntp + q;
    const int rbase = 16*mt + 4*g;
    const int tile0 = blockIdx.x * TILES_PER_BLOCK;

    // ---- stage LDS weights (once per block) ----
    for (int i = tid; i < 128*128; i += THREADS) {
        int a = i >> 7, b = i & 127;
        sBW2T[b][a] = (__bf16)W2[i];
    }
    for (int i = tid; i < 128*64; i += THREADS)
        sAW3[i >> 6][i & 63] = (__bf16)W3[i];

    if (tid < 64) {
        sy[tid >> 1][tid & 1]    = y[tile0*BM*2 + tid];
        sv[0][tid >> 1][tid & 1] = v[tile0*BM*2 + tid];
    }

    // ---- per-wave-constant weight fragments -> VGPRs ----
    bf16x8 w2b0[4], w2b1[4], w3t[4], xfrag[4];
    #pragma unroll
    for (int ks = 0; ks < 4; ++ks) {
        const float4* pA = (const float4*)(W2 + colA*128 + 8*g + 32*ks);
        const float4* pB = (const float4*)(W2 + colB*128 + 8*g + 32*ks);
        float4 a0 = pA[0], a1 = pA[1], bb0 = pB[0], bb1 = pB[1];
        bf16x8 fa = {(__bf16)a0.x,(__bf16)a0.y,(__bf16)a0.z,(__bf16)a0.w,
                     (__bf16)a1.x,(__bf16)a1.y,(__bf16)a1.z,(__bf16)a1.w};
        bf16x8 fb = {(__bf16)bb0.x,(__bf16)bb0.y,(__bf16)bb0.z,(__bf16)bb0.w,
                     (__bf16)bb1.x,(__bf16)bb1.y,(__bf16)bb1.z,(__bf16)bb1.w};
        w2b0[ks] = fa; w2b1[ks] = fb;
        bf16x8 f3;
        #pragma unroll
        for (int i = 0; i < 8; ++i)
            f3[i] = (__bf16)W3[(8*g + 32*ks + i)*64 + c3];
        w3t[ks] = f3;
        bf16x8 fx = {};
        if (ntp == 0 && q < 2) {                 // W1 frags (div GEMV)
            #pragma unroll
            for (int i = 0; i < 8; ++i)
                fx[i] = (__bf16)W1[q*128 + 8*g + 32*ks + i];
        } else if (ntp == 1 && q < 2 && ks < 2) { // W4 frags (dy GEMV)
            #pragma unroll
            for (int i = 0; i < 8; ++i)
                fx[i] = (__bf16)W4[(8*g + 32*ks + i)*2 + q];
        }
        xfrag[ks] = fx;
    }

    const float tval = tp[0];
    const float w1aA = W1[colA],       w1bA = W1[128 + colA];
    const float w1aB = W1[colB],       w1bB = W1[128 + colB];
    const float c1A  = fmaf(tval, W1[256 + colA], b1[colA]);
    const float c1B  = fmaf(tval, W1[256 + colB], b1[colB]);
    const float b2A  = b2[colA], b2B = b2[colB];
    const float b3v  = b3[c3], w40 = W4[2*c3], w41 = W4[2*c3 + 1];
    const float b4q  = (q < 2) ? b4[q] : 0.0f;

    __syncthreads();

    #pragma unroll 1
    for (int tile = tile0; tile < tile0 + TILES_PER_BLOCK; ++tile) {
        const int row0 = tile * BM;
        const int cur  = (tile - tile0) & 1;

        // ---- P1: layer 1 (VALU); sp1 stays in VGPRs (P5 C-layout) ----
        bf16x8 sp1;
        #pragma unroll
        for (int nti = 0; nti < 2; ++nti) {
            const float wa = nti ? w1aB : w1aA;
            const float wb = nti ? w1bB : w1bA;
            const float cc = nti ? c1B  : c1A;
            const int  col = nti ? colB : colA;
            #pragma unroll
            for (int reg = 0; reg < 4; ++reg) {
                const int r = rbase + reg;
                float z = fmaf(sy[r][0], wa, fmaf(sy[r][1], wb, cc));
                float h, sp; silu2(z, h, sp);
                sH1[r][col] = (__bf16)h;
                sp1[nti*4 + reg] = (__bf16)sp;
            }
        }
        __syncthreads();                          // B1

        // ---- P2: z2 = h1 @ W2 (+b2); sp2 -> VGPRs ----
        bf16x8 sp2;
        {
            f32x4 acc0 = {0,0,0,0}, acc1 = {0,0,0,0};
            const __bf16* ar  = &sH1[16*mt + q][0];
            const __bf16* br0 = &sBW2T[colA][0];
            const __bf16* br1 = &sBW2T[colB][0];
            #pragma unroll
            for (int ks = 0; ks < 4; ++ks) {
                int ko = 8*g + 32*ks;
                bf16x8 av = *(const bf16x8*)(ar + ko);
                acc0 = mfma16(av, *(const bf16x8*)(br0 + ko), acc0);
                acc1 = mfma16(av, *(const bf16x8*)(br1 + ko), acc1);
            }
            #pragma unroll
            for (int nti = 0; nti < 2; ++nti) {
                const int cc = nti ? colB : colA;
                const float bias = nti ? b2B : b2A;
                f32x4 acc = nti ? acc1 : acc0;
                #pragma unroll
                for (int reg = 0; reg < 4; ++reg) {
                    float z = acc[reg] + bias;
                    float h, sp; silu2(z, h, sp);
                    sH2[rbase + reg][cc] = (__bf16)h;
                    sp2[nti*4 + reg] = (__bf16)sp;
                }
            }
        }
        __syncthreads();                          // B2

        // ---- P3: z3 = h2 @ W3 (+b3) [B from VGPR]; h3, d3 -> LDS ----
        {
            f32x4 acc = {0,0,0,0};
            const __bf16* ar = &sH2[16*mt + q][0];
            #pragma unroll
            for (int ks = 0; ks < 4; ++ks)
                acc = mfma16(*(const bf16x8*)(ar + 8*g + 32*ks), w3t[ks], acc);
            #pragma unroll
            for (int reg = 0; reg < 4; ++reg) {
                const int rr = rbase + reg;
                float z = acc[reg] + b3v;
                float h, sp; silu2(z, h, sp);
                float g3 = fmaf(sv[cur][rr][0], w40, sv[cur][rr][1]*w41);
                sH3[rr][c3] = (__bf16)h;
                sD3[rr][c3] = (__bf16)(g3*sp);
            }
        }
        __syncthreads();                          // B3

        // ---- dy = h3 @ W4 + b4 (2 MFMAs, ntp==1 waves only) ----
        if (ntp == 1) {
            f32x4 acc = {0,0,0,0};
            const __bf16* ar = &sH3[16*mt + q][0];
            #pragma unroll
            for (int ks = 0; ks < 2; ++ks)
                acc = mfma16(*(const bf16x8*)(ar + 8*g + 32*ks), xfrag[ks], acc);
            if (q < 2) {
                #pragma unroll
                for (int reg = 0; reg < 4; ++reg)
                    out[(row0 + rbase + reg)*2 + q] = acc[reg] + b4q;
            }
        }

        // ---- P4: g2 = d3 @ W3^T ; d2 = g2*sp2 -> sH1 ----
        {
            f32x4 acc0 = {0,0,0,0}, acc1 = {0,0,0,0};
            const __bf16* ar  = &sD3[16*mt + q][0];
            const __bf16* br0 = &sAW3[colA][0];
            const __bf16* br1 = &sAW3[colB][0];
            #pragma unroll
            for (int ks = 0; ks < 2; ++ks) {
                int ko = 8*g + 32*ks;
                bf16x8 av = *(const bf16x8*)(ar + ko);
                acc0 = mfma16(av, *(const bf16x8*)(br0 + ko), acc0);
                acc1 = mfma16(av, *(const bf16x8*)(br1 + ko), acc1);
            }
            #pragma unroll
            for (int nti = 0; nti < 2; ++nti) {
                const int cc = nti ? colB : colA;
                f32x4 acc = nti ? acc1 : acc0;
                #pragma unroll
                for (int reg = 0; reg < 4; ++reg)
                    sH1[rbase + reg][cc] =
                        (__bf16)(acc[reg] * (float)sp2[nti*4 + reg]);
            }
        }
        // stage next tile's y/v under P4/P5 latency
        if (tile + 1 < tile0 + TILES_PER_BLOCK && tid < 64) {
            sy[tid >> 1][tid & 1]          = y[(row0 + BM)*2 + tid];
            sv[cur ^ 1][tid >> 1][tid & 1] = v[(row0 + BM)*2 + tid];
        }
        __syncthreads();                          // B4

        // ---- P5: g1 = d2 @ W2^T [B from VGPR]; d1 -> sH2 ----
        {
            f32x4 acc0 = {0,0,0,0}, acc1 = {0,0,0,0};
            const __bf16* ar = &sH1[16*mt + q][0];
            #pragma unroll
            for (int ks = 0; ks < 4; ++ks) {
                int ko = 8*g + 32*ks;
                bf16x8 av = *(const bf16x8*)(ar + ko);
                acc0 = mfma16(av, w2b0[ks], acc0);
                acc1 = mfma16(av, w2b1[ks], acc1);
            }
            #pragma unroll
            for (int nti = 0; nti < 2; ++nti) {
                const int aa = nti ? colB : colA;
                f32x4 acc = nti ? acc1 : acc0;
                #pragma unroll
                for (int reg = 0; reg < 4; ++reg)
                    sH2[rbase + reg][aa] =
                        (__bf16)(acc[reg] * (float)sp1[nti*4 + reg]);
            }
        }
        __syncthreads();                          // B5

        // ---- div: e = d1 @ W1^T (4 MFMAs, ntp==0 waves); -v.e -> out ----
        if (ntp == 0) {
            f32x4 acc = {0,0,0,0};
            const __bf16* ar = &sH2[16*mt + q][0];
            #pragma unroll
            for (int ks = 0; ks < 4; ++ks)
                acc = mfma16(*(const bf16x8*)(ar + 8*g + 32*ks), xfrag[ks], acc);
            #pragma unroll
            for (int reg = 0; reg < 4; ++reg) {
                const int rr = rbase + reg;
                float t0 = acc[reg] * sv[cur][rr][q & 1];
                float t1 = __shfl_xor(t0, 1);
                if (q == 0)
                    out[2*NROWS + row0 + rr] = -(t0 + t1);
            }
        }
    }
}

extern "C" void kernel_launch(void* const* d_in, const int* in_sizes, int n_in,
                              void* d_out, int out_size, void* d_ws, size_t ws_size,
                              hipStream_t stream) {
    const float* y  = (const float*)d_in[0];
    // d_in[1] = logp (unused by reference)
    const float* t  = (const float*)d_in[2];
    const float* v  = (const float*)d_in[3];
    const float* W1 = (const float*)d_in[4];
    const float* b1 = (const float*)d_in[5];
    const float* W2 = (const float*)d_in[6];
    const float* b2 = (const float*)d_in[7];
    const float* W3 = (const float*)d_in[8];
    const float* b3 = (const float*)d_in[9];
    const float* W4 = (const float*)d_in[10];
    const float* b4 = (const float*)d_in[11];
    float* out = (float*)d_out;

    cnf_kernel<<<dim3(BLOCKS), dim3(THREADS), 0, stream>>>(
        y, t, v, W1, b1, W2, b2, W3, b3, W4, b4, out);
}